// Round 1
// baseline (318.872 us; speedup 1.0000x reference)
//
#include <hip/hip_runtime.h>
#include <hip/hip_bf16.h>

typedef __attribute__((ext_vector_type(8))) short short8;
typedef __attribute__((ext_vector_type(4))) float floatx4;

__device__ __forceinline__ float sigm(float x) { return 1.0f / (1.0f + __expf(-x)); }

__device__ __forceinline__ unsigned short f2bf(float v) {
  union { __hip_bfloat16 h; unsigned short u; } cv;
  cv.h = __float2bfloat16(v);
  return cv.u;
}

// ---------------- prep: fold ia/im/bias into padded bf16 weights ----------------
// Combined channel c (0..170): c<18 -> det row c (scaled by im, bias im*(b + W.ia));
//                              c>=18 -> kpt row c-18 (bias bk). Rows 171..175 zero.
__global__ void prep_kernel(const float* __restrict__ w, const float* __restrict__ b,
                            const float* __restrict__ im, const float* __restrict__ ia,
                            const float* __restrict__ wk, const float* __restrict__ bk,
                            unsigned short* __restrict__ Wp, float* __restrict__ bias, int C) {
  const int n = blockIdx.x;   // 0..175
  const int t = threadIdx.x;  // 0..63 (one wave)
  unsigned short* wrow = Wp + (size_t)n * C;
  if (n >= 171) {
    for (int k = t; k < C; k += 64) wrow[k] = 0;
    if (t == 0) bias[n] = 0.0f;
    return;
  }
  if (n < 18) {
    const float* src = w + (size_t)n * C;
    const float sc = im[n];
    float dot = 0.0f;
    for (int k = t; k < C; k += 64) {
      float v = src[k];
      dot += v * ia[k];
      wrow[k] = f2bf(v * sc);
    }
#pragma unroll
    for (int off = 32; off > 0; off >>= 1) dot += __shfl_down(dot, off);
    if (t == 0) bias[n] = sc * (b[n] + dot);
  } else {
    const float* src = wk + (size_t)(n - 18) * C;
    for (int k = t; k < C; k += 64) wrow[k] = f2bf(src[k]);
    if (t == 0) bias[n] = bk[n - 18];
  }
}

// ---------------- fused GEMM (bf16 MFMA) + decode ----------------
#define SMEM_BYTES 46080  // max( A 9216 + B 25344 staging, 64*180*4 epilogue )

template <int SC, int C, int HW, int W>
__device__ __forceinline__ void gemm_decode(const float* __restrict__ feat,
                                            const unsigned short* __restrict__ Wp,
                                            const float* __restrict__ bias,
                                            float* __restrict__ out, int tile, char* smem) {
  constexpr float STRD = (SC == 0) ? 8.0f : (SC == 1) ? 16.0f : 32.0f;
  constexpr int ZOFF = (SC == 0) ? 0 : (SC == 1) ? 19200 : 24000;
  constexpr int AST = 72;   // A row stride (bf16): 64 + 8 pad
  constexpr int BST = 72;   // B row stride (bf16)
  constexpr int EST = 180;  // epilogue row stride (fp32)

  const int t = threadIdx.x;
  const int lane = t & 63;
  const int wv = t >> 6;       // wave 0..3
  const int l15 = lane & 15;
  const int quad = lane >> 4;

  unsigned short* Alds = (unsigned short*)smem;             // [64][72] bf16
  unsigned short* Blds = (unsigned short*)(smem + 9216);    // [176][72] bf16
  float* Elds = (float*)smem;                               // [64][180] fp32 (reuse)

  const int m0 = tile * 64;
  // staging row for this thread (handles b-boundary crossing for HW=400)
  const int mA = m0 + lane;
  const int bA = mA / HW;
  const int pA = mA - bA * HW;
  const float* fbase = feat + ((size_t)bA * C) * HW + pA + (size_t)(wv * 16) * HW;

  floatx4 acc[11];
#pragma unroll
  for (int j = 0; j < 11; ++j) acc[j] = (floatx4){0.f, 0.f, 0.f, 0.f};

  // fragment read bases: A[m=l15][k=quad*8+j], B[n=l15][k=quad*8+j]
  const unsigned short* aRd = Alds + (wv * 16 + l15) * AST + quad * 8;
  const unsigned short* bRd = Blds + l15 * BST + quad * 8;

  const int k8 = (t & 7) * 8;
  const int nr = t >> 3;

  for (int k0 = 0; k0 < C; k0 += 64) {
    __syncthreads();
    // --- stage A: 64 m x 64 k fp32 -> bf16 LDS. thread: m=lane, k = wv*16 + 0..15
    {
      const float* g = fbase + (size_t)k0 * HW;
      float v[16];
#pragma unroll
      for (int kk = 0; kk < 16; ++kk) v[kk] = g[(size_t)kk * HW];
      short8 s0, s1;
#pragma unroll
      for (int kk = 0; kk < 8; ++kk) {
        s0[kk] = (short)f2bf(v[kk]);
        s1[kk] = (short)f2bf(v[kk + 8]);
      }
      *(short8*)(Alds + lane * AST + wv * 16) = s0;
      *(short8*)(Alds + lane * AST + wv * 16 + 8) = s1;
    }
    // --- stage B: 176 n x 64 k bf16 (L2-resident). thread: n = pp*32 + t/8, 8 k's
#pragma unroll
    for (int pp = 0; pp < 6; ++pp) {
      int n = pp * 32 + nr;
      if (n < 176) {
        short8 wv8 = *(const short8*)(Wp + (size_t)n * C + k0 + k8);
        *(short8*)(Blds + n * BST + k8) = wv8;
      }
    }
    __syncthreads();
    // --- MFMA: wave computes 16 m x 176 n
#pragma unroll
    for (int h = 0; h < 2; ++h) {
      short8 af = *(const short8*)(aRd + h * 32);
#pragma unroll
      for (int j = 0; j < 11; ++j) {
        short8 bf = *(const short8*)(bRd + j * 16 * BST + h * 32);
        acc[j] = __builtin_amdgcn_mfma_f32_16x16x32_bf16(af, bf, acc[j], 0, 0, 0);
      }
    }
  }

  __syncthreads();  // staging LDS dead; reuse as epilogue tile
  // dump acc + bias: C/D layout col=l15, row=quad*4+reg
#pragma unroll
  for (int j = 0; j < 11; ++j) {
    float bj = bias[j * 16 + l15];
#pragma unroll
    for (int r = 0; r < 4; ++r) {
      int row = wv * 16 + quad * 4 + r;
      Elds[row * EST + j * 16 + l15] = acc[j][r] + bj;
    }
  }
  __syncthreads();
  // decode in place: thread handles one (row, anchor)
  if (t < 192) {
    const int rr = t & 63;
    const int a = t >> 6;
    const int m = m0 + rr;
    const int bb = m / HW;
    const int p = m - bb * HW;
    const float fx = (float)(p % W);
    const float fy = (float)(p / W);
    float aw, ah;
    if constexpr (SC == 0) {
      aw = (a == 0) ? 19.f : (a == 1) ? 44.f : 38.f;
      ah = (a == 0) ? 27.f : (a == 1) ? 40.f : 94.f;
    } else if constexpr (SC == 1) {
      aw = (a == 0) ? 96.f : (a == 1) ? 86.f : 180.f;
      ah = (a == 0) ? 68.f : (a == 1) ? 152.f : 137.f;
    } else {
      aw = (a == 0) ? 140.f : (a == 1) ? 303.f : 238.f;
      ah = (a == 0) ? 301.f : (a == 1) ? 264.f : 542.f;
    }
    float* L = Elds + rr * EST + a * 57;
    float r0 = L[0], r1 = L[1], r2 = L[2], r3 = L[3], r4 = L[4], r5 = L[5];
    L[0] = (sigm(r0) * 2.f - 0.5f + fx) * STRD;
    L[1] = (sigm(r1) * 2.f - 0.5f + fy) * STRD;
    float tw = sigm(r2) * 2.f;
    L[2] = tw * tw * aw;
    float th = sigm(r3) * 2.f;
    L[3] = th * th * ah;
    L[4] = sigm(r4);
    L[5] = sigm(r5);
#pragma unroll
    for (int kp = 0; kp < 17; ++kp) {
      float kx = L[6 + 3 * kp], ky = L[7 + 3 * kp], kc = L[8 + 3 * kp];
      L[6 + 3 * kp] = (kx * 2.f - 0.5f + fx) * STRD;
      L[7 + 3 * kp] = (ky * 2.f - 0.5f + fy) * STRD;
      L[8 + 3 * kp] = sigm(kc);
    }
  }
  __syncthreads();
  // coalesced copy-out: contiguous 57-float rows per (a, p)
  for (int i = t; i < 192 * 57; i += 256) {
    int row = i / 57;
    int jj = i - row * 57;
    int a = row >> 6, rr = row & 63;
    int m = m0 + rr;
    int bb = m / HW;
    int p = m - bb * HW;
    size_t orow = (size_t)bb * 25200 + (size_t)(ZOFF + a * HW + p);
    out[orow * 57 + jj] = Elds[rr * EST + a * 57 + jj];
  }
}

__global__ __launch_bounds__(256, 3) void main_kernel(
    const float* __restrict__ f0, const float* __restrict__ f1, const float* __restrict__ f2,
    const unsigned short* __restrict__ Wp0, const unsigned short* __restrict__ Wp1,
    const unsigned short* __restrict__ Wp2, const float* __restrict__ b0,
    const float* __restrict__ b1, const float* __restrict__ b2, float* __restrict__ out) {
  __shared__ __align__(16) char smem[SMEM_BYTES];
  const int bid = blockIdx.x;
  // longest blocks (scale 2, C=1024) first to amortize the tail
  if (bid < 100)
    gemm_decode<2, 1024, 400, 20>(f2, Wp2, b2, out, bid, smem);
  else if (bid < 500)
    gemm_decode<1, 512, 1600, 40>(f1, Wp1, b1, out, bid - 100, smem);
  else
    gemm_decode<0, 256, 6400, 80>(f0, Wp0, b0, out, bid - 500, smem);
}

extern "C" void kernel_launch(void* const* d_in, const int* in_sizes, int n_in, void* d_out,
                              int out_size, void* d_ws, size_t ws_size, hipStream_t stream) {
  const float *f[3], *ia[3], *w[3], *b[3], *im[3], *wk[3], *bk[3];
  for (int s = 0; s < 3; ++s) {
    f[s] = (const float*)d_in[7 * s + 0];
    ia[s] = (const float*)d_in[7 * s + 1];
    w[s] = (const float*)d_in[7 * s + 2];
    b[s] = (const float*)d_in[7 * s + 3];
    im[s] = (const float*)d_in[7 * s + 4];
    wk[s] = (const float*)d_in[7 * s + 5];
    bk[s] = (const float*)d_in[7 * s + 6];
  }
  // workspace layout (16B-aligned): Wp0 90112B | Wp1 180224B | Wp2 360448B | 3x bias 176 f32
  char* ws = (char*)d_ws;
  unsigned short* Wp0 = (unsigned short*)(ws + 0);
  unsigned short* Wp1 = (unsigned short*)(ws + 90112);
  unsigned short* Wp2 = (unsigned short*)(ws + 270336);
  float* bias0 = (float*)(ws + 630784);
  float* bias1 = (float*)(ws + 631488);
  float* bias2 = (float*)(ws + 632192);

  const int Cs[3] = {256, 512, 1024};
  unsigned short* Wps[3] = {Wp0, Wp1, Wp2};
  float* biases[3] = {bias0, bias1, bias2};
  for (int s = 0; s < 3; ++s)
    prep_kernel<<<176, 64, 0, stream>>>(w[s], b[s], im[s], ia[s], wk[s], bk[s], Wps[s],
                                        biases[s], Cs[s]);
  main_kernel<<<2100, 256, 0, stream>>>(f[0], f[1], f[2], Wp0, Wp1, Wp2, bias0, bias1, bias2,
                                        (float*)d_out);
}